// Round 1
// baseline (88.816 us; speedup 1.0000x reference)
//
#include <hip/hip_runtime.h>
#include <math.h>

#define CROP 96
#define WIN 11
#define OUT 86   // CROP - WIN + 1
#define IMH 1080
#define IMW 1920

__global__ __launch_bounds__(256) void ssim_blocks_kernel(
    const float* __restrict__ img,
    const float* __restrict__ imgr,
    const int* __restrict__ target,
    float* __restrict__ block_sums)
{
    __shared__ float sA[CROP * CROP];
    __shared__ float sB[CROP * CROP];
    __shared__ float vcol[2][5][CROP];
    __shared__ float red[256];

    const int blk = blockIdx.x;          // 0 .. 3*N-1
    const int s   = blk / 3;
    const int c   = blk % 3;

    const int xmin = target[s * 5 + 0];
    const int ymin = target[s * 5 + 1];

    const float* __restrict__ pa = img  + (size_t)c * IMH * IMW;
    const float* __restrict__ pb = imgr + (size_t)c * IMH * IMW;

    const int tid = threadIdx.x;

    // ---- load both crops into LDS (coalesced along rows) ----
    for (int idx = tid; idx < CROP * CROP; idx += 256) {
        const int r   = idx / CROP;
        const int col = idx - r * CROP;
        const size_t g = (size_t)(ymin + r) * IMW + (size_t)(xmin + col);
        sA[idx] = pa[g];
        sB[idx] = pb[g];
    }

    // ---- gaussian weights (f32, matches reference) ----
    float gw[WIN];
    {
        float sum = 0.f;
        #pragma unroll
        for (int k = 0; k < WIN; ++k) {
            const float cc = (float)k - (float)(WIN - 1) * 0.5f;
            gw[k] = expf(-(cc * cc) / (2.0f * 1.5f * 1.5f));
            sum += gw[k];
        }
        const float inv = 1.0f / sum;
        #pragma unroll
        for (int k = 0; k < WIN; ++k) gw[k] *= inv;
    }

    const float C1 = 6.5025f;    // (0.01*255)^2
    const float C2 = 58.5225f;   // (0.03*255)^2

    __syncthreads();

    float acc = 0.f;
    const int group = tid >> 7;    // 0 or 1 (wave-uniform: waves 0,1 vs 2,3)
    const int lane  = tid & 127;

    for (int i0 = 0; i0 < OUT; i0 += 2) {
        const int i = i0 + group;          // OUT=86 even -> i <= 85 always valid

        // stage 1: vertical 11-tap conv for all 96 columns, 5 maps
        if (lane < CROP) {
            float va = 0.f, vb = 0.f, vaa = 0.f, vbb = 0.f, vab = 0.f;
            #pragma unroll
            for (int k = 0; k < WIN; ++k) {
                const float w = gw[k];
                const float a = sA[(i + k) * CROP + lane];
                const float b = sB[(i + k) * CROP + lane];
                va  += w * a;
                vb  += w * b;
                vaa += w * a * a;
                vbb += w * b * b;
                vab += w * a * b;
            }
            vcol[group][0][lane] = va;
            vcol[group][1][lane] = vb;
            vcol[group][2][lane] = vaa;
            vcol[group][3][lane] = vbb;
            vcol[group][4][lane] = vab;
        }
        __syncthreads();

        // stage 2: horizontal 11-tap conv + SSIM per output pixel
        if (lane < OUT) {
            float mu1 = 0.f, mu2 = 0.f, eaa = 0.f, ebb = 0.f, eab = 0.f;
            #pragma unroll
            for (int x = 0; x < WIN; ++x) {
                const float w = gw[x];
                mu1 += w * vcol[group][0][lane + x];
                mu2 += w * vcol[group][1][lane + x];
                eaa += w * vcol[group][2][lane + x];
                ebb += w * vcol[group][3][lane + x];
                eab += w * vcol[group][4][lane + x];
            }
            const float mu1s = mu1 * mu1;
            const float mu2s = mu2 * mu2;
            const float mu12 = mu1 * mu2;
            const float s1  = eaa - mu1s;
            const float s2  = ebb - mu2s;
            const float s12 = eab - mu12;
            const float num = (2.f * mu12 + C1) * (2.f * s12 + C2);
            const float den = (mu1s + mu2s + C1) * (s1 + s2 + C2);
            acc += num / den;
        }
        __syncthreads();
    }

    // ---- deterministic block reduction ----
    red[tid] = acc;
    __syncthreads();
    #pragma unroll
    for (int off = 128; off > 0; off >>= 1) {
        if (tid < off) red[tid] += red[tid + off];
        __syncthreads();
    }
    if (tid == 0) block_sums[blk] = red[0];
}

__global__ __launch_bounds__(256) void ssim_finalize_kernel(
    const float* __restrict__ block_sums,
    float* __restrict__ out,
    int nblk)
{
    __shared__ float red[256];
    const int tid = threadIdx.x;
    float s = 0.f;
    for (int i = tid; i < nblk; i += 256) s += block_sums[i];
    red[tid] = s;
    __syncthreads();
    #pragma unroll
    for (int off = 128; off > 0; off >>= 1) {
        if (tid < off) red[tid] += red[tid + off];
        __syncthreads();
    }
    if (tid == 0) {
        const float mean = red[0] / ((float)nblk * (float)(OUT * OUT));
        out[0] = 5.0f * (1.0f - mean);
    }
}

extern "C" void kernel_launch(void* const* d_in, const int* in_sizes, int n_in,
                              void* d_out, int out_size, void* d_ws, size_t ws_size,
                              hipStream_t stream)
{
    const float* img  = (const float*)d_in[0];
    const float* imgr = (const float*)d_in[1];
    const int*   tgt  = (const int*)d_in[2];
    const int N = in_sizes[2] / 5;
    const int nblk = 3 * N;

    float* block_sums = (float*)d_ws;

    ssim_blocks_kernel<<<nblk, 256, 0, stream>>>(img, imgr, tgt, block_sums);
    ssim_finalize_kernel<<<1, 256, 0, stream>>>(block_sums, (float*)d_out, nblk);
}